// Round 9
// baseline (215.858 us; speedup 1.0000x reference)
//
#include <hip/hip_runtime.h>

#define N_ITEMS 65536

// ---------------- Kernel 1: qpart[z] = x @ W (K-chunk 256 per z) ----------------
__launch_bounds__(256)
__global__ void gemm_q_kernel(const float* __restrict__ A,
                              const float* __restrict__ W,
                              float* __restrict__ qpart) {
  __shared__ float As[16][132];
  __shared__ float Bs[16][132];
  const int tid = threadIdx.x;
  const int tx = tid & 15, ty = tid >> 4;
  const int rb = blockIdx.y * 128, cb = blockIdx.x * 128;
  const int kz = blockIdx.z * 256;
  const int ar = tid >> 2, ac = (tid & 3) << 2;
  const int bk = tid >> 5, bc = (tid & 31) << 2;

  float4 va0 = *(const float4*)&A[(rb + ar) * 1024 + kz + ac];
  float4 va1 = *(const float4*)&A[(rb + ar + 64) * 1024 + kz + ac];
  float4 vb0 = *(const float4*)&W[(kz + bk) * 1024 + cb + bc];
  float4 vb1 = *(const float4*)&W[(kz + bk + 8) * 1024 + cb + bc];

  float acc[8][8] = {};
  for (int k0 = 0; k0 < 256; k0 += 16) {
    As[ac + 0][ar] = va0.x; As[ac + 1][ar] = va0.y;
    As[ac + 2][ar] = va0.z; As[ac + 3][ar] = va0.w;
    As[ac + 0][ar + 64] = va1.x; As[ac + 1][ar + 64] = va1.y;
    As[ac + 2][ar + 64] = va1.z; As[ac + 3][ar + 64] = va1.w;
    *(float4*)&Bs[bk][bc] = vb0;
    *(float4*)&Bs[bk + 8][bc] = vb1;
    __syncthreads();
    if (k0 + 16 < 256) {
      va0 = *(const float4*)&A[(rb + ar) * 1024 + kz + k0 + 16 + ac];
      va1 = *(const float4*)&A[(rb + ar + 64) * 1024 + kz + k0 + 16 + ac];
      vb0 = *(const float4*)&W[(kz + k0 + 16 + bk) * 1024 + cb + bc];
      vb1 = *(const float4*)&W[(kz + k0 + 16 + bk + 8) * 1024 + cb + bc];
    }
#pragma unroll
    for (int kk = 0; kk < 16; kk++) {
      const float4 a0 = *(const float4*)&As[kk][ty << 2];
      const float4 a1 = *(const float4*)&As[kk][64 + (ty << 2)];
      const float4 b0 = *(const float4*)&Bs[kk][tx << 2];
      const float4 b1 = *(const float4*)&Bs[kk][64 + (tx << 2)];
      const float ar8[8] = {a0.x, a0.y, a0.z, a0.w, a1.x, a1.y, a1.z, a1.w};
      const float br8[8] = {b0.x, b0.y, b0.z, b0.w, b1.x, b1.y, b1.z, b1.w};
#pragma unroll
      for (int r = 0; r < 8; r++)
#pragma unroll
        for (int c = 0; c < 8; c++)
          acc[r][c] = fmaf(ar8[r], br8[c], acc[r][c]);
    }
    __syncthreads();
  }
  float* outp = qpart + blockIdx.z * 1048576;
#pragma unroll
  for (int rh = 0; rh < 2; rh++)
#pragma unroll
    for (int r = 0; r < 4; r++) {
      const int row = rb + rh * 64 + (ty << 2) + r;
      const int ri = rh * 4 + r;
      *(float4*)&outp[row * 1024 + cb + (tx << 2)] =
          make_float4(acc[ri][0], acc[ri][1], acc[ri][2], acc[ri][3]);
      *(float4*)&outp[row * 1024 + cb + 64 + (tx << 2)] =
          make_float4(acc[ri][4], acc[ri][5], acc[ri][6], acc[ri][7]);
    }
}

// ---------------- Kernel 2: lut + in-register qsq/csq + code packing ----------
// pack plane: h = dword-offset base of entry e=j*256+c in the 4-row b128
// replica table: h = j*4096 + (c>>1)*32 + (c&1)*4  (max 32740, fits u16).
__launch_bounds__(256)
__global__ void lut_kernel(const float* __restrict__ qpart,
                           const float* __restrict__ kcb,
                           const int* __restrict__ key_codes,
                           float* __restrict__ lut,
                           unsigned long long* __restrict__ pcodes,
                           uint4* __restrict__ poffs) {
  if (blockIdx.z == 8) {
    const int g0 = (((int)blockIdx.y * 4 + (int)blockIdx.x) * 256 + (int)threadIdx.x) * 4;
#pragma unroll
    for (int t = 0; t < 4; t++) {
      const int gid = g0 + t;
      unsigned long long p = 0ull;
      unsigned h[8];
#pragma unroll
      for (int j = 0; j < 8; j++) {
        const unsigned c = (unsigned)key_codes[gid * 8 + j] & 255u;
        p |= (unsigned long long)c << (8 * j);
        h[j] = (unsigned)(j * 4096) + ((c >> 1) << 5) + ((c & 1u) << 2);
      }
      pcodes[gid] = p;
      poffs[gid] = make_uint4(h[0] | (h[1] << 16), h[2] | (h[3] << 16),
                              h[4] | (h[5] << 16), h[6] | (h[7] << 16));
    }
    return;
  }

  __shared__ float As[32][68];
  __shared__ float Bs[32][68];
  const int tid = threadIdx.x;
  const int tx = tid & 15, ty = tid >> 4;
  const int m = blockIdx.z;
  const int rb = blockIdx.y * 64;
  const int cb0 = blockIdx.x * 64;
  float acc[4][4] = {};
  float qa[4] = {}, cs[4] = {};
  for (int k0 = 0; k0 < 128; k0 += 32) {
#pragma unroll
    for (int l = 0; l < 2; l++) {
      const int e = tid + l * 256;
      const int row = e >> 3, c4 = (e & 7) << 2;
      const int qidx = (rb + row) * 1024 + m * 128 + k0 + c4;
      const float4 p0 = *(const float4*)&qpart[qidx];
      const float4 p1 = *(const float4*)&qpart[qidx + 1048576];
      const float4 p2 = *(const float4*)&qpart[qidx + 2097152];
      const float4 p3 = *(const float4*)&qpart[qidx + 3145728];
      const float4 va = make_float4(p0.x + p1.x + p2.x + p3.x,
                                    p0.y + p1.y + p2.y + p3.y,
                                    p0.z + p1.z + p2.z + p3.z,
                                    p0.w + p1.w + p2.w + p3.w);
      As[c4 + 0][row] = va.x; As[c4 + 1][row] = va.y;
      As[c4 + 2][row] = va.z; As[c4 + 3][row] = va.w;
      const float4 vb = *(const float4*)&kcb[(m * 256 + cb0 + row) * 128 + k0 + c4];
      Bs[c4 + 0][row] = vb.x; Bs[c4 + 1][row] = vb.y;
      Bs[c4 + 2][row] = vb.z; Bs[c4 + 3][row] = vb.w;
    }
    __syncthreads();
#pragma unroll
    for (int kk = 0; kk < 32; kk++) {
      const float4 a = *(const float4*)&As[kk][ty << 2];
      const float4 b = *(const float4*)&Bs[kk][tx << 2];
      const float ar[4] = {a.x, a.y, a.z, a.w};
      const float br[4] = {b.x, b.y, b.z, b.w};
#pragma unroll
      for (int r = 0; r < 4; r++)
#pragma unroll
        for (int c = 0; c < 4; c++)
          acc[r][c] = fmaf(ar[r], br[c], acc[r][c]);
#pragma unroll
      for (int r = 0; r < 4; r++) qa[r] = fmaf(ar[r], ar[r], qa[r]);
#pragma unroll
      for (int c = 0; c < 4; c++) cs[c] = fmaf(br[c], br[c], cs[c]);
    }
    __syncthreads();
  }
#pragma unroll
  for (int r = 0; r < 4; r++) {
    const int row = rb + (ty << 2) + r;
    const int col = cb0 + (tx << 2);
    float4 v;
    v.x = qa[r] + cs[0] - 2.0f * acc[r][0];
    v.y = qa[r] + cs[1] - 2.0f * acc[r][1];
    v.z = qa[r] + cs[2] - 2.0f * acc[r][2];
    v.w = qa[r] + cs[3] - 2.0f * acc[r][3];
    *(float4*)&lut[row * 2048 + m * 256 + col] = v;
  }
}

// ---------------- Kernel 3a: 4-ROW ADC scan, i32 entries, b128 lookups -------
// Block g scans rows 4g..4g+3 in one pass: entry e holds 4 rows' quantized
// LUT values (4 x i32 = 16B); one ds_read_b128 serves 4 rows (amortizes the
// ~5.9cyc/wave LDS issue rate; b128 = 12 cyc for 4x the data, m134).
// 4 replicas, replica r in banks 8r..8r+7: dword D(e,r,row) =
// (e>>1)*32 + r*8 + (e&1)*4 + row; lane uses r=lane&3 -> 16 lanes/replica
// split by e&1 over two bank-quads (skew ~1.16x). 128KB dyn LDS exactly.
// Quantization identical to r8 (scale 64, per-(row,m) mean-centered, i32).
extern __shared__ char dyn_lds[];

__launch_bounds__(1024)
__global__ void scan4r_kernel(const float* __restrict__ lut,
                              const uint4* __restrict__ poffs,
                              unsigned* __restrict__ cand_d,
                              unsigned short* __restrict__ cand_n) {
  int* repw = (int*)dyn_lds;
  const char* repb = dyn_lds;
  const int tid = threadIdx.x;
  const int g = blockIdx.x;

  // ---- init: thread -> (row rr, 8 entries of one segment) ----
  {
    const int rr = tid >> 8;                 // row within quad
    const int e0 = (tid & 255) << 3;         // 8 entries, single segment
    const int row = (g << 2) + rr;
    const float4 v0 = *(const float4*)&lut[row * 2048 + e0];
    const float4 v1 = *(const float4*)&lut[row * 2048 + e0 + 4];
    float s8 = v0.x + v0.y + v0.z + v0.w + v1.x + v1.y + v1.z + v1.w;
#pragma unroll
    for (int off = 1; off <= 16; off <<= 1) s8 += __shfl_xor(s8, off);
    const float mean = s8 * (1.0f / 256.0f);
    const float vals[8] = {v0.x, v0.y, v0.z, v0.w, v1.x, v1.y, v1.z, v1.w};
#pragma unroll
    for (int k = 0; k < 8; k++) {
      const int e = e0 + k;
      const int q = (int)rintf((vals[k] - mean) * 64.0f);
      const int D = ((e >> 1) << 5) + ((e & 1) << 2) + rr;
#pragma unroll
      for (int r2 = 0; r2 < 4; r2++) repw[D + r2 * 8] = q;
    }
  }
  __syncthreads();

  // ---- scan: 64 items/lane, 8 b128 lookups/item serving 4 rows ----
  const int rbyte = (tid & 3) << 5;          // replica base (r*32 bytes)
  int d0[4], d1[4], i0[4], i1[4];
#pragma unroll
  for (int r2 = 0; r2 < 4; r2++) {
    d0[r2] = 0x7FFFFFFF; d1[r2] = 0x7FFFFFFF; i0[r2] = 0; i1[r2] = 0;
  }

  uint4 oc = poffs[tid];
  uint4 nc = poffs[tid + 1024];
  for (int it = 0; it < 64; it++) {
    const int n = tid + (it << 10);
    uint4 nn2 = nc;
    if (it < 62) nn2 = poffs[n + 2048];
    int s[4];
    {
      const int4 q = *(const int4*)(repb + ((oc.x & 0xFFFFu) << 2) + rbyte);
      s[0] = q.x; s[1] = q.y; s[2] = q.z; s[3] = q.w;
    }
#define LK4(HV) { const int4 q = *(const int4*)(repb + ((HV) << 2) + rbyte); \
                  s[0] += q.x; s[1] += q.y; s[2] += q.z; s[3] += q.w; }
    LK4(oc.x >> 16)
    LK4(oc.y & 0xFFFFu)
    LK4(oc.y >> 16)
    LK4(oc.z & 0xFFFFu)
    LK4(oc.z >> 16)
    LK4(oc.w & 0xFFFFu)
    LK4(oc.w >> 16)
#undef LK4
#pragma unroll
    for (int r2 = 0; r2 < 4; r2++) {
      const int sv = s[r2];
      if (sv < d1[r2]) {
        if (sv < d0[r2]) { d1[r2] = d0[r2]; i1[r2] = i0[r2]; d0[r2] = sv; i0[r2] = n; }
        else             { d1[r2] = sv; i1[r2] = n; }
      }
    }
    oc = nc; nc = nn2;
  }

#pragma unroll
  for (int r2 = 0; r2 < 4; r2++) {
    const int base = ((g << 2) + r2) * 2048 + tid * 2;
    *(uint2*)&cand_d[base] = make_uint2((unsigned)(d0[r2] + 0x40000000),
                                        (unsigned)(d1[r2] + 0x40000000));
    *(unsigned*)&cand_n[base] = (unsigned)i0[r2] | ((unsigned)i1[r2] << 16);
  }
}

// ---------------- Kernel 3b: fallback 64KB scan (verified) ----------------
__launch_bounds__(512)
__global__ void scan16_kernel(const float* __restrict__ lut,
                              const unsigned long long* __restrict__ pcodes,
                              unsigned* __restrict__ cand_d,
                              unsigned short* __restrict__ cand_n) {
  __shared__ short sRep[32768];
  const int tid = threadIdx.x;
  const int b = blockIdx.x;

  const float4 v4 = *(const float4*)&lut[b * 2048 + tid * 4];
  float s4 = v4.x + v4.y + v4.z + v4.w;
#pragma unroll
  for (int off = 32; off > 0; off >>= 1) s4 += __shfl_xor(s4, off);
  const float mean = s4 * (1.0f / 256.0f);

  const float vals[4] = {v4.x, v4.y, v4.z, v4.w};
#pragma unroll
  for (int k2 = 0; k2 < 4; k2++) {
    float f = (vals[k2] - mean) * 64.0f;
    f = fmaxf(fminf(f, 32000.0f), -32000.0f);
    const int iv = (int)rintf(f);
    const unsigned hw = (unsigned)(unsigned short)iv;
    const unsigned wrd = hw | (hw << 16);
    const uint4 wv = make_uint4(wrd, wrd, wrd, wrd);
    const int e = tid * 4 + k2;
    *(uint4*)&((unsigned*)sRep)[e * 8] = wv;
    *(uint4*)&((unsigned*)sRep)[e * 8 + 4] = wv;
  }
  __syncthreads();

  const int r = tid & 15;
  int d0 = 0x7FFFFFFF, d1 = 0x7FFFFFFF, d2 = 0x7FFFFFFF, d3 = 0x7FFFFFFF;
  int i0 = 0, i1 = 0, i2 = 0, i3 = 0;

  unsigned long long c8 = pcodes[tid];
  for (int it = 0; it < 128; it++) {
    const int n = tid + (it << 9);
    unsigned long long nxt = 0ull;
    if (it < 127) nxt = pcodes[n + 512];
    const unsigned lo = (unsigned)c8;
    const unsigned hi = (unsigned)(c8 >> 32);
    int s;
    s  = sRep[(((lo      ) & 255u) << 4) + r        ];
    s += sRep[(((lo >>  8) & 255u) << 4) + r +  4096];
    s += sRep[(((lo >> 16) & 255u) << 4) + r +  8192];
    s += sRep[(((lo >> 24)       ) << 4) + r + 12288];
    s += sRep[(((hi      ) & 255u) << 4) + r + 16384];
    s += sRep[(((hi >>  8) & 255u) << 4) + r + 20480];
    s += sRep[(((hi >> 16) & 255u) << 4) + r + 24576];
    s += sRep[(((hi >> 24)       ) << 4) + r + 28672];
    if (s < d3) {
      if (s < d1) {
        if (s < d0) { d3 = d2; i3 = i2; d2 = d1; i2 = i1; d1 = d0; i1 = i0; d0 = s; i0 = n; }
        else        { d3 = d2; i3 = i2; d2 = d1; i2 = i1; d1 = s; i1 = n; }
      } else {
        if (s < d2) { d3 = d2; i3 = i2; d2 = s; i2 = n; }
        else        { d3 = s; i3 = n; }
      }
    }
    c8 = nxt;
  }

  const int base = b * 2048 + tid * 4;
  const uint4 dv = make_uint4((unsigned)(d0 + 0x40000000), (unsigned)(d1 + 0x40000000),
                              (unsigned)(d2 + 0x40000000), (unsigned)(d3 + 0x40000000));
  *(uint4*)&cand_d[base] = dv;
  const unsigned ni01 = (unsigned)i0 | ((unsigned)i1 << 16);
  const unsigned ni23 = (unsigned)i2 | ((unsigned)i3 << 16);
  *(uint2*)&cand_n[base] = make_uint2(ni01, ni23);
}

// ---------------- Kernel 4: SORT-FREE select + softmax + value gather --------
__launch_bounds__(256)
__global__ void select_kernel(const unsigned* __restrict__ cand_d,
                              const unsigned short* __restrict__ cand_n,
                              const int* __restrict__ value_codes,
                              const float* __restrict__ vcb,
                              const float* __restrict__ bias,
                              float* __restrict__ out) {
  __shared__ unsigned sredw[4];
  __shared__ unsigned long long clist[256];
  __shared__ float sw[256];
  __shared__ int svc[2048];
  __shared__ int scnt;
  __shared__ float sWsum;

  const int tid = threadIdx.x;
  const int b = blockIdx.x;

  const uint4 a0 = *(const uint4*)&cand_d[b * 2048 + tid * 8];
  const uint4 a1 = *(const uint4*)&cand_d[b * 2048 + tid * 8 + 4];
  const uint4 nn = *(const uint4*)&cand_n[b * 2048 + tid * 8];
  unsigned dk[8] = {a0.x, a0.y, a0.z, a0.w, a1.x, a1.y, a1.z, a1.w};
  unsigned ni[8] = {nn.x & 0xFFFFu, nn.x >> 16, nn.y & 0xFFFFu, nn.y >> 16,
                    nn.z & 0xFFFFu, nn.z >> 16, nn.w & 0xFFFFu, nn.w >> 16};

  if (tid == 0) scnt = 0;
  unsigned mn = dk[0];
#pragma unroll
  for (int j = 1; j < 8; j++) mn = (dk[j] < mn) ? dk[j] : mn;
#pragma unroll
  for (int off = 32; off > 0; off >>= 1) {
    const unsigned o = __shfl_xor(mn, off);
    mn = (o < mn) ? o : mn;
  }
  if ((tid & 63) == 0) sredw[tid >> 6] = mn;
  __syncthreads();
  unsigned sMin = sredw[0];
  sMin = (sredw[1] < sMin) ? sredw[1] : sMin;
  sMin = (sredw[2] < sMin) ? sredw[2] : sMin;
  sMin = (sredw[3] < sMin) ? sredw[3] : sMin;
  const unsigned lim = sMin + 2048u;

  const int lane = tid & 63;
  const unsigned long long lm = (1ull << lane) - 1ull;
#pragma unroll
  for (int j = 0; j < 8; j++) {
    const bool pred = dk[j] <= lim;
    const unsigned long long mask = __ballot(pred);
    int base = 0;
    if (lane == 0 && mask) base = atomicAdd(&scnt, __popcll(mask));
    base = __shfl(base, 0);
    if (pred) {
      const int pos = base + __popcll(mask & lm);
      if (pos < 256) clist[pos] = ((unsigned long long)dk[j] << 32) | ni[j];
    }
  }
  __syncthreads();
  const int cnt = min(scnt, 256);

  if (tid < cnt) {
    const int gap = (int)((unsigned)(clist[tid] >> 32)) - (int)sMin;
    sw[tid] = __expf((float)gap * -0.015625f);
  }
  for (int i = tid; i < (cnt << 3); i += 256)
    svc[i] = value_codes[((int)(clist[i >> 3] & 0xFFFFFFFFu)) * 8 + (i & 7)];
  __syncthreads();

  if (tid < 64) {
    float s = 0.f;
    for (int j = tid; j < cnt; j += 64) s += sw[j];
#pragma unroll
    for (int off = 32; off > 0; off >>= 1) s += __shfl_xor(s, off);
    if (tid == 0) sWsum = s;
  }
  __syncthreads();
  const float inv = 1.0f / sWsum;

  const int c0 = tid << 3;
  const int mv = c0 >> 8;
  const int off = c0 & 255;
  float4 acc0 = make_float4(0.f, 0.f, 0.f, 0.f);
  float4 acc1 = make_float4(0.f, 0.f, 0.f, 0.f);
  const float* vbase = vcb + mv * 65536 + off;
  for (int k = 0; k < cnt; k++) {
    const float w = sw[k];
    const float* vp = vbase + svc[(k << 3) + mv] * 256;
    const float4 v0 = *(const float4*)vp;
    const float4 v1 = *(const float4*)(vp + 4);
    acc0.x = fmaf(w, v0.x, acc0.x); acc0.y = fmaf(w, v0.y, acc0.y);
    acc0.z = fmaf(w, v0.z, acc0.z); acc0.w = fmaf(w, v0.w, acc0.w);
    acc1.x = fmaf(w, v1.x, acc1.x); acc1.y = fmaf(w, v1.y, acc1.y);
    acc1.z = fmaf(w, v1.z, acc1.z); acc1.w = fmaf(w, v1.w, acc1.w);
  }
  const float4 b0 = *(const float4*)&bias[c0];
  const float4 b1 = *(const float4*)&bias[c0 + 4];
  *(float4*)&out[b * 2048 + c0] =
      make_float4(fmaf(acc0.x, inv, b0.x), fmaf(acc0.y, inv, b0.y),
                  fmaf(acc0.z, inv, b0.z), fmaf(acc0.w, inv, b0.w));
  *(float4*)&out[b * 2048 + c0 + 4] =
      make_float4(fmaf(acc1.x, inv, b1.x), fmaf(acc1.y, inv, b1.y),
                  fmaf(acc1.z, inv, b1.z), fmaf(acc1.w, inv, b1.w));
}

// ---------------- launch ----------------
extern "C" void kernel_launch(void* const* d_in, const int* in_sizes, int n_in,
                              void* d_out, int out_size, void* d_ws, size_t ws_size,
                              hipStream_t stream) {
  const float* x    = (const float*)d_in[0];
  const float* W    = (const float*)d_in[1];
  const float* kcb  = (const float*)d_in[2];
  const float* vcb  = (const float*)d_in[3];
  const float* bias = (const float*)d_in[4];
  const int* key_codes   = (const int*)d_in[5];
  const int* value_codes = (const int*)d_in[6];
  float* out = (float*)d_out;

  // ws (25.5 MB): qpart 16MB | lut 8MB | poffs 1MB | pcodes 0.5MB.
  // cand buffers alias qpart (dead after lut; written by scan afterwards).
  float* qpart = (float*)d_ws;
  float* lut   = qpart + 4194304;
  uint4* poffs = (uint4*)(lut + 2097152);
  unsigned long long* pcodes = (unsigned long long*)(poffs + 65536);
  unsigned* cand_d = (unsigned*)d_ws;
  unsigned short* cand_n = (unsigned short*)(cand_d + 2097152);

  hipLaunchKernelGGL(gemm_q_kernel, dim3(8, 8, 4), dim3(256), 0, stream,
                     x, W, qpart);
  hipLaunchKernelGGL(lut_kernel, dim3(4, 16, 9), dim3(256), 0, stream,
                     qpart, kcb, key_codes, lut, pcodes, poffs);

  const hipError_t attr_rc = hipFuncSetAttribute(
      (const void*)scan4r_kernel, hipFuncAttributeMaxDynamicSharedMemorySize, 131072);
  if (attr_rc == hipSuccess) {
    hipLaunchKernelGGL(scan4r_kernel, dim3(256), dim3(1024), 131072, stream,
                       lut, poffs, cand_d, cand_n);
  } else {
    hipLaunchKernelGGL(scan16_kernel, dim3(1024), dim3(512), 0, stream,
                       lut, pcodes, cand_d, cand_n);
  }

  hipLaunchKernelGGL(select_kernel, dim3(1024), dim3(256), 0, stream,
                     cand_d, cand_n, value_codes, vcb, bias, out);
}

// Round 10
// 197.374 us; speedup vs baseline: 1.0936x; 1.0936x over previous
//
#include <hip/hip_runtime.h>

#define N_ITEMS 65536

// ---------------- Kernel 1: qpart[z] = x @ W (K-chunk 256 per z) ----------------
__launch_bounds__(256)
__global__ void gemm_q_kernel(const float* __restrict__ A,
                              const float* __restrict__ W,
                              float* __restrict__ qpart) {
  __shared__ float As[16][132];
  __shared__ float Bs[16][132];
  const int tid = threadIdx.x;
  const int tx = tid & 15, ty = tid >> 4;
  const int rb = blockIdx.y * 128, cb = blockIdx.x * 128;
  const int kz = blockIdx.z * 256;
  const int ar = tid >> 2, ac = (tid & 3) << 2;
  const int bk = tid >> 5, bc = (tid & 31) << 2;

  float4 va0 = *(const float4*)&A[(rb + ar) * 1024 + kz + ac];
  float4 va1 = *(const float4*)&A[(rb + ar + 64) * 1024 + kz + ac];
  float4 vb0 = *(const float4*)&W[(kz + bk) * 1024 + cb + bc];
  float4 vb1 = *(const float4*)&W[(kz + bk + 8) * 1024 + cb + bc];

  float acc[8][8] = {};
  for (int k0 = 0; k0 < 256; k0 += 16) {
    As[ac + 0][ar] = va0.x; As[ac + 1][ar] = va0.y;
    As[ac + 2][ar] = va0.z; As[ac + 3][ar] = va0.w;
    As[ac + 0][ar + 64] = va1.x; As[ac + 1][ar + 64] = va1.y;
    As[ac + 2][ar + 64] = va1.z; As[ac + 3][ar + 64] = va1.w;
    *(float4*)&Bs[bk][bc] = vb0;
    *(float4*)&Bs[bk + 8][bc] = vb1;
    __syncthreads();
    if (k0 + 16 < 256) {
      va0 = *(const float4*)&A[(rb + ar) * 1024 + kz + k0 + 16 + ac];
      va1 = *(const float4*)&A[(rb + ar + 64) * 1024 + kz + k0 + 16 + ac];
      vb0 = *(const float4*)&W[(kz + k0 + 16 + bk) * 1024 + cb + bc];
      vb1 = *(const float4*)&W[(kz + k0 + 16 + bk + 8) * 1024 + cb + bc];
    }
#pragma unroll
    for (int kk = 0; kk < 16; kk++) {
      const float4 a0 = *(const float4*)&As[kk][ty << 2];
      const float4 a1 = *(const float4*)&As[kk][64 + (ty << 2)];
      const float4 b0 = *(const float4*)&Bs[kk][tx << 2];
      const float4 b1 = *(const float4*)&Bs[kk][64 + (tx << 2)];
      const float ar8[8] = {a0.x, a0.y, a0.z, a0.w, a1.x, a1.y, a1.z, a1.w};
      const float br8[8] = {b0.x, b0.y, b0.z, b0.w, b1.x, b1.y, b1.z, b1.w};
#pragma unroll
      for (int r = 0; r < 8; r++)
#pragma unroll
        for (int c = 0; c < 8; c++)
          acc[r][c] = fmaf(ar8[r], br8[c], acc[r][c]);
    }
    __syncthreads();
  }
  float* outp = qpart + blockIdx.z * 1048576;
#pragma unroll
  for (int rh = 0; rh < 2; rh++)
#pragma unroll
    for (int r = 0; r < 4; r++) {
      const int row = rb + rh * 64 + (ty << 2) + r;
      const int ri = rh * 4 + r;
      *(float4*)&outp[row * 1024 + cb + (tx << 2)] =
          make_float4(acc[ri][0], acc[ri][1], acc[ri][2], acc[ri][3]);
      *(float4*)&outp[row * 1024 + cb + 64 + (tx << 2)] =
          make_float4(acc[ri][4], acc[ri][5], acc[ri][6], acc[ri][7]);
    }
}

// ---------------- Kernel 2: lut + in-register qsq/csq + code packing ----------
// pack plane: h = segment-local byte offset in the 2-row scan table:
//   h = (c>>1)*128 + (c&1)*4   (max 16260, fits u16).
// Segment base (j*16384) and replica base (8r) are added in the scan kernel.
__launch_bounds__(256)
__global__ void lut_kernel(const float* __restrict__ qpart,
                           const float* __restrict__ kcb,
                           const int* __restrict__ key_codes,
                           float* __restrict__ lut,
                           unsigned long long* __restrict__ pcodes,
                           uint4* __restrict__ poffs) {
  if (blockIdx.z == 8) {
    const int g0 = (((int)blockIdx.y * 4 + (int)blockIdx.x) * 256 + (int)threadIdx.x) * 4;
#pragma unroll
    for (int t = 0; t < 4; t++) {
      const int gid = g0 + t;
      unsigned long long p = 0ull;
      unsigned h[8];
#pragma unroll
      for (int j = 0; j < 8; j++) {
        const unsigned c = (unsigned)key_codes[gid * 8 + j] & 255u;
        p |= (unsigned long long)c << (8 * j);
        h[j] = ((c >> 1) << 7) | ((c & 1u) << 2);
      }
      pcodes[gid] = p;
      poffs[gid] = make_uint4(h[0] | (h[1] << 16), h[2] | (h[3] << 16),
                              h[4] | (h[5] << 16), h[6] | (h[7] << 16));
    }
    return;
  }

  __shared__ float As[32][68];
  __shared__ float Bs[32][68];
  const int tid = threadIdx.x;
  const int tx = tid & 15, ty = tid >> 4;
  const int m = blockIdx.z;
  const int rb = blockIdx.y * 64;
  const int cb0 = blockIdx.x * 64;
  float acc[4][4] = {};
  float qa[4] = {}, cs[4] = {};
  for (int k0 = 0; k0 < 128; k0 += 32) {
#pragma unroll
    for (int l = 0; l < 2; l++) {
      const int e = tid + l * 256;
      const int row = e >> 3, c4 = (e & 7) << 2;
      const int qidx = (rb + row) * 1024 + m * 128 + k0 + c4;
      const float4 p0 = *(const float4*)&qpart[qidx];
      const float4 p1 = *(const float4*)&qpart[qidx + 1048576];
      const float4 p2 = *(const float4*)&qpart[qidx + 2097152];
      const float4 p3 = *(const float4*)&qpart[qidx + 3145728];
      const float4 va = make_float4(p0.x + p1.x + p2.x + p3.x,
                                    p0.y + p1.y + p2.y + p3.y,
                                    p0.z + p1.z + p2.z + p3.z,
                                    p0.w + p1.w + p2.w + p3.w);
      As[c4 + 0][row] = va.x; As[c4 + 1][row] = va.y;
      As[c4 + 2][row] = va.z; As[c4 + 3][row] = va.w;
      const float4 vb = *(const float4*)&kcb[(m * 256 + cb0 + row) * 128 + k0 + c4];
      Bs[c4 + 0][row] = vb.x; Bs[c4 + 1][row] = vb.y;
      Bs[c4 + 2][row] = vb.z; Bs[c4 + 3][row] = vb.w;
    }
    __syncthreads();
#pragma unroll
    for (int kk = 0; kk < 32; kk++) {
      const float4 a = *(const float4*)&As[kk][ty << 2];
      const float4 b = *(const float4*)&Bs[kk][tx << 2];
      const float ar[4] = {a.x, a.y, a.z, a.w};
      const float br[4] = {b.x, b.y, b.z, b.w};
#pragma unroll
      for (int r = 0; r < 4; r++)
#pragma unroll
        for (int c = 0; c < 4; c++)
          acc[r][c] = fmaf(ar[r], br[c], acc[r][c]);
#pragma unroll
      for (int r = 0; r < 4; r++) qa[r] = fmaf(ar[r], ar[r], qa[r]);
#pragma unroll
      for (int c = 0; c < 4; c++) cs[c] = fmaf(br[c], br[c], cs[c]);
    }
    __syncthreads();
  }
#pragma unroll
  for (int r = 0; r < 4; r++) {
    const int row = rb + (ty << 2) + r;
    const int col = cb0 + (tx << 2);
    float4 v;
    v.x = qa[r] + cs[0] - 2.0f * acc[r][0];
    v.y = qa[r] + cs[1] - 2.0f * acc[r][1];
    v.z = qa[r] + cs[2] - 2.0f * acc[r][2];
    v.w = qa[r] + cs[3] - 2.0f * acc[r][3];
    *(float4*)&lut[row * 2048 + m * 256 + col] = v;
  }
}

// ---------------- Kernel 3a: 2-ROW ADC scan, i16-pair dwords, 16 replicas ----
// One ds_read_b32 serves 2 rows (halves wave-LDS-ops -> issue floor 40us,
// model: ops/CU x 5.9cyc validated on r8's 80.1us). Replica r owns banks
// {2r, 2r+1}: dword D(e,r) = (e>>1)*32 + (e&1) + 2r; lane uses r=lane&15 ->
// 4 lanes/replica split Binomial(4,1/2) over 2 banks: max load ~4 < 5.9
// issue -> conflicts hidden (b128's per-phase compounding, r9's failure,
// does not apply to single-dword reads). i32 accumulation after unpack:
// quantization and candidate sets bit-identical to r8. 136KB dyn LDS.
extern __shared__ char dyn_lds[];

__launch_bounds__(1024)
__global__ void scan2r_kernel(const float* __restrict__ lut,
                              const uint4* __restrict__ poffs,
                              unsigned* __restrict__ cand_d,
                              unsigned short* __restrict__ cand_n) {
  char* repb = dyn_lds;                              // 131072 B table
  unsigned* repw = (unsigned*)dyn_lds;
  short* temps = (short*)(dyn_lds + 131072);         // 2048 x 2 i16 (8 KB)
  unsigned* tempw = (unsigned*)(dyn_lds + 131072);
  const int tid = threadIdx.x;
  const int g = blockIdx.x;

  // ---- quantize: wave w -> (row rr = w&1, segment seg = w>>1) ----
  {
    const int w = tid >> 6, lane = tid & 63;
    const int rr = w & 1, seg = w >> 1;
    const int row = (g << 1) + rr;
    const int e0 = seg * 256 + lane * 4;
    const float4 v4 = *(const float4*)&lut[row * 2048 + e0];
    float s4 = v4.x + v4.y + v4.z + v4.w;
#pragma unroll
    for (int off = 32; off > 0; off >>= 1) s4 += __shfl_xor(s4, off);
    const float mean = s4 * (1.0f / 256.0f);
    const float vals[4] = {v4.x, v4.y, v4.z, v4.w};
#pragma unroll
    for (int k = 0; k < 4; k++) {
      float f = (vals[k] - mean) * 64.0f;
      f = fmaxf(fminf(f, 32000.0f), -32000.0f);
      temps[(e0 + k) * 2 + rr] = (short)(int)rintf(f);
    }
  }
  __syncthreads();

  // ---- replicate: entry-dword e -> D(e,r), lane-staggered r to spread banks
  {
    const int lane = tid & 63;
    const unsigned v0 = tempw[tid * 2];      // entry 2*tid   (e&1 = 0)
    const unsigned v1 = tempw[tid * 2 + 1];  // entry 2*tid+1 (e&1 = 1)
    const int Dbase = tid * 32;
#pragma unroll
    for (int k = 0; k < 16; k++) {
      const int r = (k + lane) & 15;
      repw[Dbase + 2 * r] = v0;
      repw[Dbase + 1 + 2 * r] = v1;
    }
  }
  __syncthreads();

  // ---- scan: 64 items/lane, 8 dword lookups/item serving both rows ----
  const int r = tid & 15;
  const char* base0 = repb + (r << 3);            // segments 0..3 via imm offs
  const char* base1 = repb + 65536 + (r << 3);    // segments 4..7
  int d0a = 0x7FFFFFFF, d1a = 0x7FFFFFFF, i0a = 0, i1a = 0;
  int d0b = 0x7FFFFFFF, d1b = 0x7FFFFFFF, i0b = 0, i1b = 0;

  uint4 oc = poffs[tid];
  uint4 nc = poffs[tid + 1024];
  for (int it = 0; it < 64; it++) {
    const int n = tid + (it << 10);
    uint4 nn2 = nc;
    if (it < 62) nn2 = poffs[n + 2048];
    unsigned wv;
    int s0, s1;
    wv = *(const unsigned*)(base0 + (oc.x & 0xFFFFu));
    s0 = (int)(short)wv; s1 = ((int)wv) >> 16;
#define LK(B, HV, OFS) { wv = *(const unsigned*)((B) + (HV) + (OFS)); \
    s0 += (int)(short)wv; s1 += ((int)wv) >> 16; }
    LK(base0, oc.x >> 16, 16384)
    LK(base0, oc.y & 0xFFFFu, 32768)
    LK(base0, oc.y >> 16, 49152)
    LK(base1, oc.z & 0xFFFFu, 0)
    LK(base1, oc.z >> 16, 16384)
    LK(base1, oc.w & 0xFFFFu, 32768)
    LK(base1, oc.w >> 16, 49152)
#undef LK
    if (s0 < d1a) {
      if (s0 < d0a) { d1a = d0a; i1a = i0a; d0a = s0; i0a = n; }
      else          { d1a = s0; i1a = n; }
    }
    if (s1 < d1b) {
      if (s1 < d0b) { d1b = d0b; i1b = i0b; d0b = s1; i0b = n; }
      else          { d1b = s1; i1b = n; }
    }
    oc = nc; nc = nn2;
  }

  {
    const int ba = (g << 1) * 2048 + tid * 2;
    *(uint2*)&cand_d[ba] = make_uint2((unsigned)(d0a + 0x40000000),
                                      (unsigned)(d1a + 0x40000000));
    *(unsigned*)&cand_n[ba] = (unsigned)i0a | ((unsigned)i1a << 16);
    const int bb = ((g << 1) + 1) * 2048 + tid * 2;
    *(uint2*)&cand_d[bb] = make_uint2((unsigned)(d0b + 0x40000000),
                                      (unsigned)(d1b + 0x40000000));
    *(unsigned*)&cand_n[bb] = (unsigned)i0b | ((unsigned)i1b << 16);
  }
}

// ---------------- Kernel 3b: fallback 64KB scan (verified) ----------------
__launch_bounds__(512)
__global__ void scan16_kernel(const float* __restrict__ lut,
                              const unsigned long long* __restrict__ pcodes,
                              unsigned* __restrict__ cand_d,
                              unsigned short* __restrict__ cand_n) {
  __shared__ short sRep[32768];
  const int tid = threadIdx.x;
  const int b = blockIdx.x;

  const float4 v4 = *(const float4*)&lut[b * 2048 + tid * 4];
  float s4 = v4.x + v4.y + v4.z + v4.w;
#pragma unroll
  for (int off = 32; off > 0; off >>= 1) s4 += __shfl_xor(s4, off);
  const float mean = s4 * (1.0f / 256.0f);

  const float vals[4] = {v4.x, v4.y, v4.z, v4.w};
#pragma unroll
  for (int k2 = 0; k2 < 4; k2++) {
    float f = (vals[k2] - mean) * 64.0f;
    f = fmaxf(fminf(f, 32000.0f), -32000.0f);
    const int iv = (int)rintf(f);
    const unsigned hw = (unsigned)(unsigned short)iv;
    const unsigned wrd = hw | (hw << 16);
    const uint4 wv = make_uint4(wrd, wrd, wrd, wrd);
    const int e = tid * 4 + k2;
    *(uint4*)&((unsigned*)sRep)[e * 8] = wv;
    *(uint4*)&((unsigned*)sRep)[e * 8 + 4] = wv;
  }
  __syncthreads();

  const int r = tid & 15;
  int d0 = 0x7FFFFFFF, d1 = 0x7FFFFFFF, d2 = 0x7FFFFFFF, d3 = 0x7FFFFFFF;
  int i0 = 0, i1 = 0, i2 = 0, i3 = 0;

  unsigned long long c8 = pcodes[tid];
  for (int it = 0; it < 128; it++) {
    const int n = tid + (it << 9);
    unsigned long long nxt = 0ull;
    if (it < 127) nxt = pcodes[n + 512];
    const unsigned lo = (unsigned)c8;
    const unsigned hi = (unsigned)(c8 >> 32);
    int s;
    s  = sRep[(((lo      ) & 255u) << 4) + r        ];
    s += sRep[(((lo >>  8) & 255u) << 4) + r +  4096];
    s += sRep[(((lo >> 16) & 255u) << 4) + r +  8192];
    s += sRep[(((lo >> 24)       ) << 4) + r + 12288];
    s += sRep[(((hi      ) & 255u) << 4) + r + 16384];
    s += sRep[(((hi >>  8) & 255u) << 4) + r + 20480];
    s += sRep[(((hi >> 16) & 255u) << 4) + r + 24576];
    s += sRep[(((hi >> 24)       ) << 4) + r + 28672];
    if (s < d3) {
      if (s < d1) {
        if (s < d0) { d3 = d2; i3 = i2; d2 = d1; i2 = i1; d1 = d0; i1 = i0; d0 = s; i0 = n; }
        else        { d3 = d2; i3 = i2; d2 = d1; i2 = i1; d1 = s; i1 = n; }
      } else {
        if (s < d2) { d3 = d2; i3 = i2; d2 = s; i2 = n; }
        else        { d3 = s; i3 = n; }
      }
    }
    c8 = nxt;
  }

  const int base = b * 2048 + tid * 4;
  const uint4 dv = make_uint4((unsigned)(d0 + 0x40000000), (unsigned)(d1 + 0x40000000),
                              (unsigned)(d2 + 0x40000000), (unsigned)(d3 + 0x40000000));
  *(uint4*)&cand_d[base] = dv;
  const unsigned ni01 = (unsigned)i0 | ((unsigned)i1 << 16);
  const unsigned ni23 = (unsigned)i2 | ((unsigned)i3 << 16);
  *(uint2*)&cand_n[base] = make_uint2(ni01, ni23);
}

// ---------------- Kernel 4: SORT-FREE select + softmax + value gather --------
__launch_bounds__(256)
__global__ void select_kernel(const unsigned* __restrict__ cand_d,
                              const unsigned short* __restrict__ cand_n,
                              const int* __restrict__ value_codes,
                              const float* __restrict__ vcb,
                              const float* __restrict__ bias,
                              float* __restrict__ out) {
  __shared__ unsigned sredw[4];
  __shared__ unsigned long long clist[256];
  __shared__ float sw[256];
  __shared__ int svc[2048];
  __shared__ int scnt;
  __shared__ float sWsum;

  const int tid = threadIdx.x;
  const int b = blockIdx.x;

  const uint4 a0 = *(const uint4*)&cand_d[b * 2048 + tid * 8];
  const uint4 a1 = *(const uint4*)&cand_d[b * 2048 + tid * 8 + 4];
  const uint4 nn = *(const uint4*)&cand_n[b * 2048 + tid * 8];
  unsigned dk[8] = {a0.x, a0.y, a0.z, a0.w, a1.x, a1.y, a1.z, a1.w};
  unsigned ni[8] = {nn.x & 0xFFFFu, nn.x >> 16, nn.y & 0xFFFFu, nn.y >> 16,
                    nn.z & 0xFFFFu, nn.z >> 16, nn.w & 0xFFFFu, nn.w >> 16};

  if (tid == 0) scnt = 0;
  unsigned mn = dk[0];
#pragma unroll
  for (int j = 1; j < 8; j++) mn = (dk[j] < mn) ? dk[j] : mn;
#pragma unroll
  for (int off = 32; off > 0; off >>= 1) {
    const unsigned o = __shfl_xor(mn, off);
    mn = (o < mn) ? o : mn;
  }
  if ((tid & 63) == 0) sredw[tid >> 6] = mn;
  __syncthreads();
  unsigned sMin = sredw[0];
  sMin = (sredw[1] < sMin) ? sredw[1] : sMin;
  sMin = (sredw[2] < sMin) ? sredw[2] : sMin;
  sMin = (sredw[3] < sMin) ? sredw[3] : sMin;
  const unsigned lim = sMin + 2048u;

  const int lane = tid & 63;
  const unsigned long long lm = (1ull << lane) - 1ull;
#pragma unroll
  for (int j = 0; j < 8; j++) {
    const bool pred = dk[j] <= lim;
    const unsigned long long mask = __ballot(pred);
    int base = 0;
    if (lane == 0 && mask) base = atomicAdd(&scnt, __popcll(mask));
    base = __shfl(base, 0);
    if (pred) {
      const int pos = base + __popcll(mask & lm);
      if (pos < 256) clist[pos] = ((unsigned long long)dk[j] << 32) | ni[j];
    }
  }
  __syncthreads();
  const int cnt = min(scnt, 256);

  if (tid < cnt) {
    const int gap = (int)((unsigned)(clist[tid] >> 32)) - (int)sMin;
    sw[tid] = __expf((float)gap * -0.015625f);
  }
  for (int i = tid; i < (cnt << 3); i += 256)
    svc[i] = value_codes[((int)(clist[i >> 3] & 0xFFFFFFFFu)) * 8 + (i & 7)];
  __syncthreads();

  if (tid < 64) {
    float s = 0.f;
    for (int j = tid; j < cnt; j += 64) s += sw[j];
#pragma unroll
    for (int off = 32; off > 0; off >>= 1) s += __shfl_xor(s, off);
    if (tid == 0) sWsum = s;
  }
  __syncthreads();
  const float inv = 1.0f / sWsum;

  const int c0 = tid << 3;
  const int mv = c0 >> 8;
  const int off = c0 & 255;
  float4 acc0 = make_float4(0.f, 0.f, 0.f, 0.f);
  float4 acc1 = make_float4(0.f, 0.f, 0.f, 0.f);
  const float* vbase = vcb + mv * 65536 + off;
  for (int k = 0; k < cnt; k++) {
    const float w = sw[k];
    const float* vp = vbase + svc[(k << 3) + mv] * 256;
    const float4 v0 = *(const float4*)vp;
    const float4 v1 = *(const float4*)(vp + 4);
    acc0.x = fmaf(w, v0.x, acc0.x); acc0.y = fmaf(w, v0.y, acc0.y);
    acc0.z = fmaf(w, v0.z, acc0.z); acc0.w = fmaf(w, v0.w, acc0.w);
    acc1.x = fmaf(w, v1.x, acc1.x); acc1.y = fmaf(w, v1.y, acc1.y);
    acc1.z = fmaf(w, v1.z, acc1.z); acc1.w = fmaf(w, v1.w, acc1.w);
  }
  const float4 b0 = *(const float4*)&bias[c0];
  const float4 b1 = *(const float4*)&bias[c0 + 4];
  *(float4*)&out[b * 2048 + c0] =
      make_float4(fmaf(acc0.x, inv, b0.x), fmaf(acc0.y, inv, b0.y),
                  fmaf(acc0.z, inv, b0.z), fmaf(acc0.w, inv, b0.w));
  *(float4*)&out[b * 2048 + c0 + 4] =
      make_float4(fmaf(acc1.x, inv, b1.x), fmaf(acc1.y, inv, b1.y),
                  fmaf(acc1.z, inv, b1.z), fmaf(acc1.w, inv, b1.w));
}

// ---------------- launch ----------------
extern "C" void kernel_launch(void* const* d_in, const int* in_sizes, int n_in,
                              void* d_out, int out_size, void* d_ws, size_t ws_size,
                              hipStream_t stream) {
  const float* x    = (const float*)d_in[0];
  const float* W    = (const float*)d_in[1];
  const float* kcb  = (const float*)d_in[2];
  const float* vcb  = (const float*)d_in[3];
  const float* bias = (const float*)d_in[4];
  const int* key_codes   = (const int*)d_in[5];
  const int* value_codes = (const int*)d_in[6];
  float* out = (float*)d_out;

  // ws (25.5 MB): qpart 16MB | lut 8MB | poffs 1MB | pcodes 0.5MB.
  // cand buffers alias qpart (dead after lut; written by scan afterwards).
  float* qpart = (float*)d_ws;
  float* lut   = qpart + 4194304;
  uint4* poffs = (uint4*)(lut + 2097152);
  unsigned long long* pcodes = (unsigned long long*)(poffs + 65536);
  unsigned* cand_d = (unsigned*)d_ws;
  unsigned short* cand_n = (unsigned short*)(cand_d + 2097152);

  hipLaunchKernelGGL(gemm_q_kernel, dim3(8, 8, 4), dim3(256), 0, stream,
                     x, W, qpart);
  hipLaunchKernelGGL(lut_kernel, dim3(4, 16, 9), dim3(256), 0, stream,
                     qpart, kcb, key_codes, lut, pcodes, poffs);

  const hipError_t attr_rc = hipFuncSetAttribute(
      (const void*)scan2r_kernel, hipFuncAttributeMaxDynamicSharedMemorySize, 139264);
  if (attr_rc == hipSuccess) {
    hipLaunchKernelGGL(scan2r_kernel, dim3(512), dim3(1024), 139264, stream,
                       lut, poffs, cand_d, cand_n);
  } else {
    hipLaunchKernelGGL(scan16_kernel, dim3(1024), dim3(512), 0, stream,
                       lut, pcodes, cand_d, cand_n);
  }

  hipLaunchKernelGGL(select_kernel, dim3(1024), dim3(256), 0, stream,
                     cand_d, cand_n, value_codes, vcb, bias, out);
}